// Round 3
// baseline (1357.117 us; speedup 1.0000x reference)
//
#include <hip/hip_runtime.h>
#include <hip/hip_bf16.h>

// Problem constants (fixed shapes from setup_inputs)
#define NROWS 65536   // 64*32*32
#define DIM   256
#define KCODE 1024
#define NUMEL (NROWS * DIM)   // 16777216

// ---------------- prep: E^T for coalesced gather ----------------
// emb is [DIM][KCODE] row-major; et is [KCODE][DIM]
__global__ __launch_bounds__(256) void vq_prep_t(const float* __restrict__ emb,
                                                 float* __restrict__ et) {
    __shared__ float t[32][33];
    int bk = blockIdx.x & 31;   // k-tile
    int bd = blockIdx.x >> 5;   // d-tile
    int lx = threadIdx.x & 31;
    int ly = threadIdx.x >> 5;
#pragma unroll
    for (int i = 0; i < 4; ++i)
        t[ly + i * 8][lx] = emb[(bd * 32 + ly + i * 8) * KCODE + bk * 32 + lx];
    __syncthreads();
#pragma unroll
    for (int i = 0; i < 4; ++i)
        et[(bk * 32 + ly + i * 8) * DIM + bd * 32 + lx] = t[lx][ly + i * 8];
}

// ---------------- prep: cn[k] = np.sum(emb*emb, axis=0) ----------------
// numpy outer-axis reduce: strictly sequential over d, each square rounded
// separately. contract(off) prevents fma fusing (s + v*v must round twice).
__global__ __launch_bounds__(256) void vq_prep_cn(const float* __restrict__ emb,
                                                  float* __restrict__ cn) {
#pragma clang fp contract(off)
    int k = blockIdx.x * 256 + threadIdx.x;  // grid 4
    float s = 0.f;
    for (int d = 0; d < DIM; ++d) {
        float v = emb[d * KCODE + k];
        float sq = v * v;
        s = s + sq;
    }
    cn[k] = s;
}

// ---------------- prep: rn[row] = np.sum(x*x, axis=1) ----------------
// numpy pairwise_sum(n=256) = pw(128) + pw(128); each 128-block via the
// AVX512 SIMD path (nlanes=16): r0..r3 zmm accumulators folded once,
// sum = (r0+r1)+(r2+r3), then gcc _mm512_reduce_add_ps tree:
// 16->8->4 halving adds, final (v0+v2)+(v1+v3).
// Emulated: 16 threads per row = the 16 zmm lanes; shfl_down width 16.
__global__ __launch_bounds__(256) void vq_prep_rn(const float* __restrict__ x,
                                                  float* __restrict__ rn) {
#pragma clang fp contract(off)
    int l = threadIdx.x & 15;      // avx512 lane
    int r = threadIdx.x >> 4;      // row within block (16 rows/block)
    int row = blockIdx.x * 16 + r; // grid 4096
    const float* xr = x + (size_t)row * DIM;
    float blk[2];
    for (int b = 0; b < 2; ++b) {
        const float* p = xr + b * 128 + l;
        float a0 = p[0],  a4 = p[64];
        float a1 = p[16], a5 = p[80];
        float a2 = p[32], a6 = p[96];
        float a3 = p[48], a7 = p[112];
        // squares rounded individually (numpy materializes flat*flat first)
        float s0 = a0 * a0, s4 = a4 * a4;
        float s1 = a1 * a1, s5 = a5 * a5;
        float s2 = a2 * a2, s6 = a6 * a6;
        float s3 = a3 * a3, s7 = a7 * a7;
        float r0 = s0 + s4;          // r0 += load(a+64)
        float r1 = s1 + s5;
        float r2 = s2 + s6;
        float r3 = s3 + s7;
        float v = (r0 + r1) + (r2 + r3);        // per-lane vector sum
        float u = v + __shfl_down(v, 8, 16);    // 512 -> 256
        float w = u + __shfl_down(u, 4, 16);    // 256 -> 128
        float t = w + __shfl_down(w, 2, 16);    // lanes (0+2, 1+3)
        float z = t + __shfl_down(t, 1, 16);    // (v0+v2)+(v1+v3)
        blk[b] = z;
    }
    if (l == 0) rn[row] = blk[0] + blk[1];
}

// ---------------- main: np-exact fp32 distances + argmin ----------------
// sim accumulated per (row,code) as ONE fp32 accumulator, sequential d=0..255,
// explicit fmaf -> bit-matches OpenBLAS sgemm micro-kernel.
// dist = fl(fl(rn + cn_k) - 2*sim)  (numpy's broadcast + then - rounding).
__global__ __launch_bounds__(256) void vq_argmin(const float* __restrict__ x,
                                                 const float* __restrict__ emb,
                                                 const float* __restrict__ cn,
                                                 const float* __restrict__ rn,
                                                 int* __restrict__ idx_out) {
    __shared__ float smem[2 * 32 * 132];   // 8448 floats = 33 KB
    float* XT = smem;                // XT[d*132 + m]
    float* ES = smem + 32 * 132;     // ES[d*132 + k]

    const int tid = threadIdx.x;
    const int tx = tid & 15;         // code group
    const int ty = tid >> 4;         // row group
    const int m0 = blockIdx.x * 128;

    float rnv[8];
#pragma unroll
    for (int i = 0; i < 8; ++i) rnv[i] = rn[m0 + ty * 8 + i];

    float best[8];
    int   bidx[8];
#pragma unroll
    for (int i = 0; i < 8; ++i) { best[i] = 3.402823466e38f; bidx[i] = 0; }

    for (int kt = 0; kt < 8; ++kt) {            // 8 code-tiles of 128
        float acc[8][8];
#pragma unroll
        for (int i = 0; i < 8; ++i)
#pragma unroll
            for (int j = 0; j < 8; ++j) acc[i][j] = 0.f;

        float cnv[8];
#pragma unroll
        for (int j = 0; j < 8; ++j) cnv[j] = cn[kt * 128 + tx * 8 + j];

        for (int dc = 0; dc < 8; ++dc) {        // 8 D-chunks of 32, ascending
            __syncthreads();
#pragma unroll
            for (int i = 0; i < 4; ++i) {
                int flat = tid + i * 256;
                int row = flat >> 3, c4 = flat & 7;
                float4 v = *(const float4*)&x[(size_t)(m0 + row) * DIM + dc * 32 + c4 * 4];
                XT[(c4 * 4 + 0) * 132 + row] = v.x;
                XT[(c4 * 4 + 1) * 132 + row] = v.y;
                XT[(c4 * 4 + 2) * 132 + row] = v.z;
                XT[(c4 * 4 + 3) * 132 + row] = v.w;
            }
#pragma unroll
            for (int i = 0; i < 4; ++i) {
                int flat = tid + i * 256;
                int d = flat >> 5, c4 = flat & 31;
                float4 v = *(const float4*)&emb[(size_t)(dc * 32 + d) * KCODE + kt * 128 + c4 * 4];
                *(float4*)&ES[d * 132 + c4 * 4] = v;
            }
            __syncthreads();
#pragma unroll 4
            for (int d = 0; d < 32; ++d) {      // ascending within chunk
                float4 xa = *(float4*)&XT[d * 132 + ty * 8];
                float4 xb = *(float4*)&XT[d * 132 + ty * 8 + 4];
                float4 ea = *(float4*)&ES[d * 132 + tx * 8];
                float4 eb = *(float4*)&ES[d * 132 + tx * 8 + 4];
                float xv[8] = {xa.x, xa.y, xa.z, xa.w, xb.x, xb.y, xb.z, xb.w};
                float ev[8] = {ea.x, ea.y, ea.z, ea.w, eb.x, eb.y, eb.z, eb.w};
#pragma unroll
                for (int i = 0; i < 8; ++i)
#pragma unroll
                    for (int j = 0; j < 8; ++j)
                        acc[i][j] = __builtin_fmaf(xv[i], ev[j], acc[i][j]);
            }
        }
        // epilogue: np-exact dist, fold into running argmin.
        // k ascends across (kt, j) per thread -> strict < = first occurrence.
#pragma unroll
        for (int j = 0; j < 8; ++j) {
            int k = kt * 128 + tx * 8 + j;
#pragma unroll
            for (int i = 0; i < 8; ++i) {
                float t = rnv[i] + cnv[j];          // fl(rn + cn)   (broadcast add)
                float s = t - 2.0f * acc[i][j];     // fl(t - 2*sim) (2*sim exact)
                if (s < best[i]) { best[i] = s; bidx[i] = k; }
            }
        }
    }

    // cross-thread (tx) merge via LDS; min value, lowest index on ties
    __syncthreads();
    float* rbv = smem;                        // [128][17] best value
    int*   rbi = (int*)(smem + 2176);         // [128][17] best index
#pragma unroll
    for (int i = 0; i < 8; ++i) {
        int r = ty * 8 + i;
        rbv[r * 17 + tx] = best[i];
        rbi[r * 17 + tx] = bidx[i];
    }
    __syncthreads();
    if (tid < 128) {
        float bv = 3.402823466e38f;
        int   bi = 0x7fffffff;
#pragma unroll
        for (int t = 0; t < 16; ++t) {
            float v  = rbv[tid * 17 + t];
            int   k2 = rbi[tid * 17 + t];
            if (v < bv || (v == bv && k2 < bi)) { bv = v; bi = k2; }
        }
        idx_out[m0 + tid] = bi;
    }
}

// ---------------- gather + loss partial ----------------
__global__ __launch_bounds__(256) void vq_gather(const float* __restrict__ x,
                                                 const float* __restrict__ et,
                                                 const int* __restrict__ idx,
                                                 float* __restrict__ out,
                                                 float* __restrict__ loss_acc) {
    int n = blockIdx.x;
    int d = threadIdx.x;
    int k = idx[n];
    float q  = et[(size_t)k * DIM + d];
    float xv = x[(size_t)n * DIM + d];
    out[(size_t)n * DIM + d] = xv + (q - xv);   // straight-through (np: x + (q-x))
    float diff = q - xv;
    float sq = diff * diff;
#pragma unroll
    for (int off = 32; off > 0; off >>= 1) sq += __shfl_down(sq, off);
    __shared__ float w4[4];
    if ((threadIdx.x & 63) == 0) w4[threadIdx.x >> 6] = sq;
    __syncthreads();
    if (threadIdx.x == 0) atomicAdd(loss_acc, w4[0] + w4[1] + w4[2] + w4[3]);
}

__global__ void vq_finalize(const float* __restrict__ loss_acc,
                            float* __restrict__ out) {
    // loss = (BETA + 1) * mean((q-x)^2) = 1.25 * sum / NUMEL
    out[NUMEL] = 1.25f * loss_acc[0] / 16777216.f;
}

// ---------------- launch ----------------
extern "C" void kernel_launch(void* const* d_in, const int* in_sizes, int n_in,
                              void* d_out, int out_size, void* d_ws, size_t ws_size,
                              hipStream_t stream) {
    const float* x   = (const float*)d_in[0];   // [65536][256]
    const float* emb = (const float*)d_in[1];   // [256][1024]
    float* out = (float*)d_out;                 // [NUMEL] quantized + [1] loss

    // workspace carve (bytes): et 1MB | cn 4KB | rn 256KB | idx 256KB | loss 4B
    char* ws = (char*)d_ws;
    size_t off = 0;
    float* et       = (float*)(ws + off); off += (size_t)KCODE * DIM * 4;
    float* cn       = (float*)(ws + off); off += KCODE * 4;
    float* rn       = (float*)(ws + off); off += (size_t)NROWS * 4;
    int*   idx      = (int*)  (ws + off); off += (size_t)NROWS * 4;
    float* loss_acc = (float*)(ws + off); off += 4;

    hipMemsetAsync(loss_acc, 0, 4, stream);
    vq_prep_t <<<256,  256, 0, stream>>>(emb, et);
    vq_prep_cn<<<4,    256, 0, stream>>>(emb, cn);
    vq_prep_rn<<<4096, 256, 0, stream>>>(x, rn);
    vq_argmin <<<NROWS / 128, 256, 0, stream>>>(x, emb, cn, rn, idx);
    vq_gather <<<NROWS, 256, 0, stream>>>(x, et, idx, out, loss_acc);
    vq_finalize<<<1, 1, 0, stream>>>(loss_acc, out);
}

// Round 4
// 560.148 us; speedup vs baseline: 2.4228x; 2.4228x over previous
//
#include <hip/hip_runtime.h>
#include <hip/hip_bf16.h>

// Problem constants (fixed shapes from setup_inputs)
#define NROWS 65536   // 64*32*32
#define DIM   256
#define KCODE 1024
#define NUMEL (NROWS * DIM)   // 16777216

// ---------------- prep: E^T for coalesced gather ----------------
// emb is [DIM][KCODE] row-major; et is [KCODE][DIM]
__global__ __launch_bounds__(256) void vq_prep_t(const float* __restrict__ emb,
                                                 float* __restrict__ et) {
    __shared__ float t[32][33];
    int bk = blockIdx.x & 31;   // k-tile
    int bd = blockIdx.x >> 5;   // d-tile
    int lx = threadIdx.x & 31;
    int ly = threadIdx.x >> 5;
#pragma unroll
    for (int i = 0; i < 4; ++i)
        t[ly + i * 8][lx] = emb[(bd * 32 + ly + i * 8) * KCODE + bk * 32 + lx];
    __syncthreads();
#pragma unroll
    for (int i = 0; i < 4; ++i)
        et[(bk * 32 + ly + i * 8) * DIM + bd * 32 + lx] = t[lx][ly + i * 8];
}

// ---------------- prep: cn[k] = np.sum(emb*emb, axis=0) ----------------
// BIT-EXACT vs numpy: strictly sequential over d, square and add rounded
// separately (contract off). DO NOT CHANGE ORDER.
__global__ __launch_bounds__(256) void vq_prep_cn(const float* __restrict__ emb,
                                                  float* __restrict__ cn) {
#pragma clang fp contract(off)
    int k = blockIdx.x * 256 + threadIdx.x;  // grid 4
    float s = 0.f;
    for (int d = 0; d < DIM; ++d) {
        float v = emb[d * KCODE + k];
        float sq = v * v;
        s = s + sq;
    }
    cn[k] = s;
}

// ---------------- prep: rn[row] = np.sum(x*x, axis=1) ----------------
// BIT-EXACT vs numpy pairwise_sum(256) = 128+128, AVX512 lane tree.
// DO NOT CHANGE ORDER.
__global__ __launch_bounds__(256) void vq_prep_rn(const float* __restrict__ x,
                                                  float* __restrict__ rn) {
#pragma clang fp contract(off)
    int l = threadIdx.x & 15;      // avx512 lane
    int r = threadIdx.x >> 4;      // row within block (16 rows/block)
    int row = blockIdx.x * 16 + r; // grid 4096
    const float* xr = x + (size_t)row * DIM;
    float blk[2];
    for (int b = 0; b < 2; ++b) {
        const float* p = xr + b * 128 + l;
        float a0 = p[0],  a4 = p[64];
        float a1 = p[16], a5 = p[80];
        float a2 = p[32], a6 = p[96];
        float a3 = p[48], a7 = p[112];
        float s0 = a0 * a0, s4 = a4 * a4;
        float s1 = a1 * a1, s5 = a5 * a5;
        float s2 = a2 * a2, s6 = a6 * a6;
        float s3 = a3 * a3, s7 = a7 * a7;
        float r0 = s0 + s4;
        float r1 = s1 + s5;
        float r2 = s2 + s6;
        float r3 = s3 + s7;
        float v = (r0 + r1) + (r2 + r3);
        float u = v + __shfl_down(v, 8, 16);
        float w = u + __shfl_down(u, 4, 16);
        float t = w + __shfl_down(w, 2, 16);
        float z = t + __shfl_down(t, 1, 16);
        blk[b] = z;
    }
    if (l == 0) rn[row] = blk[0] + blk[1];
}

// ---------------- main: np-exact fp32 distances + argmin ----------------
// BIT-EXACT: one fp32 accumulator per (row,code), sequential d=0..255 with
// explicit fmaf (sgemm micro-kernel); dist = fl(fl(rn+cn) - 2*sim).
__global__ __launch_bounds__(256) void vq_argmin(const float* __restrict__ x,
                                                 const float* __restrict__ emb,
                                                 const float* __restrict__ cn,
                                                 const float* __restrict__ rn,
                                                 int* __restrict__ idx_out) {
    __shared__ float smem[2 * 32 * 132];   // 8448 floats = 33 KB
    float* XT = smem;                // XT[d*132 + m]
    float* ES = smem + 32 * 132;     // ES[d*132 + k]

    const int tid = threadIdx.x;
    const int tx = tid & 15;         // code group
    const int ty = tid >> 4;         // row group
    const int m0 = blockIdx.x * 128;

    float rnv[8];
#pragma unroll
    for (int i = 0; i < 8; ++i) rnv[i] = rn[m0 + ty * 8 + i];

    float best[8];
    int   bidx[8];
#pragma unroll
    for (int i = 0; i < 8; ++i) { best[i] = 3.402823466e38f; bidx[i] = 0; }

    for (int kt = 0; kt < 8; ++kt) {            // 8 code-tiles of 128
        float acc[8][8];
#pragma unroll
        for (int i = 0; i < 8; ++i)
#pragma unroll
            for (int j = 0; j < 8; ++j) acc[i][j] = 0.f;

        float cnv[8];
#pragma unroll
        for (int j = 0; j < 8; ++j) cnv[j] = cn[kt * 128 + tx * 8 + j];

        for (int dc = 0; dc < 8; ++dc) {        // 8 D-chunks of 32, ascending
            __syncthreads();
#pragma unroll
            for (int i = 0; i < 4; ++i) {
                int flat = tid + i * 256;
                int row = flat >> 3, c4 = flat & 7;
                float4 v = *(const float4*)&x[(size_t)(m0 + row) * DIM + dc * 32 + c4 * 4];
                XT[(c4 * 4 + 0) * 132 + row] = v.x;
                XT[(c4 * 4 + 1) * 132 + row] = v.y;
                XT[(c4 * 4 + 2) * 132 + row] = v.z;
                XT[(c4 * 4 + 3) * 132 + row] = v.w;
            }
#pragma unroll
            for (int i = 0; i < 4; ++i) {
                int flat = tid + i * 256;
                int d = flat >> 5, c4 = flat & 31;
                float4 v = *(const float4*)&emb[(size_t)(dc * 32 + d) * KCODE + kt * 128 + c4 * 4];
                *(float4*)&ES[d * 132 + c4 * 4] = v;
            }
            __syncthreads();
#pragma unroll 4
            for (int d = 0; d < 32; ++d) {      // ascending within chunk
                float4 xa = *(float4*)&XT[d * 132 + ty * 8];
                float4 xb = *(float4*)&XT[d * 132 + ty * 8 + 4];
                float4 ea = *(float4*)&ES[d * 132 + tx * 8];
                float4 eb = *(float4*)&ES[d * 132 + tx * 8 + 4];
                float xv[8] = {xa.x, xa.y, xa.z, xa.w, xb.x, xb.y, xb.z, xb.w};
                float ev[8] = {ea.x, ea.y, ea.z, ea.w, eb.x, eb.y, eb.z, eb.w};
#pragma unroll
                for (int i = 0; i < 8; ++i)
#pragma unroll
                    for (int j = 0; j < 8; ++j)
                        acc[i][j] = __builtin_fmaf(xv[i], ev[j], acc[i][j]);
            }
        }
        // epilogue: np-exact dist; k ascends across (kt,j) -> strict < = first.
#pragma unroll
        for (int j = 0; j < 8; ++j) {
            int k = kt * 128 + tx * 8 + j;
#pragma unroll
            for (int i = 0; i < 8; ++i) {
                float t = rnv[i] + cnv[j];
                float s = t - 2.0f * acc[i][j];
                if (s < best[i]) { best[i] = s; bidx[i] = k; }
            }
        }
    }

    // cross-thread (tx) merge via LDS; min value, lowest index on ties
    __syncthreads();
    float* rbv = smem;                        // [128][17] best value
    int*   rbi = (int*)(smem + 2176);         // [128][17] best index
#pragma unroll
    for (int i = 0; i < 8; ++i) {
        int r = ty * 8 + i;
        rbv[r * 17 + tx] = best[i];
        rbi[r * 17 + tx] = bidx[i];
    }
    __syncthreads();
    if (tid < 128) {
        float bv = 3.402823466e38f;
        int   bi = 0x7fffffff;
#pragma unroll
        for (int t = 0; t < 16; ++t) {
            float v  = rbv[tid * 17 + t];
            int   k2 = rbi[tid * 17 + t];
            if (v < bv || (v == bv && k2 < bi)) { bv = v; bi = k2; }
        }
        idx_out[m0 + tid] = bi;
    }
}

// ---------------- gather + loss (grid-stride, 1 atomic/block) ----------------
// 2048 blocks x 256 threads, float4/lane, 8 iters. A 64-lane wave covers
// exactly one row per iter (64*4 = 256 elems) -> idx[row] is wave-uniform.
__global__ __launch_bounds__(256) void vq_gather(const float* __restrict__ x,
                                                 const float* __restrict__ et,
                                                 const int* __restrict__ idx,
                                                 float* __restrict__ out,
                                                 float* __restrict__ loss_acc) {
    const int tid = threadIdx.x;
    float lsum = 0.f;
#pragma unroll
    for (int it = 0; it < 8; ++it) {
        size_t g   = (size_t)blockIdx.x * 256 + tid + (size_t)it * (2048 * 256);
        int    row = (int)(g >> 6);          // 64 float4 per row
        int    d4  = (int)(g & 63);
        int    k   = idx[row];               // wave-uniform broadcast
        float4 q4  = *(const float4*)&et[(size_t)k * DIM + d4 * 4];
        float4 x4  = *(const float4*)&x[g * 4];
        // np: out = fl(x + fl(q - x)) elementwise; no mul -> no contraction
        float d0 = q4.x - x4.x, d1 = q4.y - x4.y;
        float d2 = q4.z - x4.z, d3 = q4.w - x4.w;
        float4 o4 = make_float4(x4.x + d0, x4.y + d1, x4.z + d2, x4.w + d3);
        *(float4*)&out[g * 4] = o4;
        lsum += d0 * d0 + d1 * d1 + d2 * d2 + d3 * d3;
    }
    // wave reduce then block reduce; ONE atomic per block
#pragma unroll
    for (int off = 32; off > 0; off >>= 1) lsum += __shfl_down(lsum, off);
    __shared__ float w4[4];
    if ((tid & 63) == 0) w4[tid >> 6] = lsum;
    __syncthreads();
    if (tid == 0) atomicAdd(loss_acc, w4[0] + w4[1] + w4[2] + w4[3]);
}

__global__ void vq_finalize(const float* __restrict__ loss_acc,
                            float* __restrict__ out) {
    // loss = (BETA + 1) * mean((q-x)^2) = 1.25 * sum / NUMEL
    out[NUMEL] = 1.25f * loss_acc[0] / 16777216.f;
}

// ---------------- launch ----------------
extern "C" void kernel_launch(void* const* d_in, const int* in_sizes, int n_in,
                              void* d_out, int out_size, void* d_ws, size_t ws_size,
                              hipStream_t stream) {
    const float* x   = (const float*)d_in[0];   // [65536][256]
    const float* emb = (const float*)d_in[1];   // [256][1024]
    float* out = (float*)d_out;                 // [NUMEL] quantized + [1] loss

    // workspace carve (bytes): et 1MB | cn 4KB | rn 256KB | idx 256KB | loss 4B
    char* ws = (char*)d_ws;
    size_t off = 0;
    float* et       = (float*)(ws + off); off += (size_t)KCODE * DIM * 4;
    float* cn       = (float*)(ws + off); off += KCODE * 4;
    float* rn       = (float*)(ws + off); off += (size_t)NROWS * 4;
    int*   idx      = (int*)  (ws + off); off += (size_t)NROWS * 4;
    float* loss_acc = (float*)(ws + off); off += 4;

    hipMemsetAsync(loss_acc, 0, 4, stream);
    vq_prep_t <<<256,  256, 0, stream>>>(emb, et);
    vq_prep_cn<<<4,    256, 0, stream>>>(emb, cn);
    vq_prep_rn<<<4096, 256, 0, stream>>>(x, rn);
    vq_argmin <<<NROWS / 128, 256, 0, stream>>>(x, emb, cn, rn, idx);
    vq_gather <<<2048,  256, 0, stream>>>(x, et, idx, out, loss_acc);
    vq_finalize<<<1, 1, 0, stream>>>(loss_acc, out);
}

// Round 5
// 324.519 us; speedup vs baseline: 4.1819x; 1.7261x over previous
//
#include <hip/hip_runtime.h>
#include <hip/hip_bf16.h>

// Problem constants (fixed shapes from setup_inputs)
#define NROWS 65536   // 64*32*32
#define DIM   256
#define KCODE 1024
#define NUMEL (NROWS * DIM)   // 16777216
#define MARGIN 0.25f          // ~8 sigma of f16-MFMA distance noise

typedef _Float16 half8 __attribute__((ext_vector_type(8)));
typedef float    f32x4 __attribute__((ext_vector_type(4)));

// ---------------- prep: E^T fp32 (gather) + E^T f16 (MFMA) ----------------
// emb [DIM][KCODE] row-major -> et [KCODE][DIM] fp32, ef [KCODE][DIM] f16
__global__ __launch_bounds__(256) void vq_prep_te(const float* __restrict__ emb,
                                                  float* __restrict__ et,
                                                  _Float16* __restrict__ ef) {
    __shared__ float t[32][33];
    int bk = blockIdx.x & 31;   // k-tile
    int bd = blockIdx.x >> 5;   // d-tile
    int lx = threadIdx.x & 31;
    int ly = threadIdx.x >> 5;
#pragma unroll
    for (int i = 0; i < 4; ++i)
        t[ly + i * 8][lx] = emb[(bd * 32 + ly + i * 8) * KCODE + bk * 32 + lx];
    __syncthreads();
#pragma unroll
    for (int i = 0; i < 4; ++i) {
        float v = t[lx][ly + i * 8];
        int o = (bk * 32 + ly + i * 8) * DIM + bd * 32 + lx;
        et[o] = v;
        ef[o] = (_Float16)v;   // RNE
    }
}

// ---------------- prep: cn[k] = np.sum(emb*emb, axis=0) ----------------
// BIT-EXACT vs numpy: sequential d, square and add rounded separately.
__global__ __launch_bounds__(256) void vq_prep_cn(const float* __restrict__ emb,
                                                  float* __restrict__ cn) {
#pragma clang fp contract(off)
    int k = blockIdx.x * 256 + threadIdx.x;  // grid 4
    float s = 0.f;
    for (int d = 0; d < DIM; ++d) {
        float v = emb[d * KCODE + k];
        float sq = v * v;
        s = s + sq;
    }
    cn[k] = s;
}

// ---------------- main: f16 MFMA distances + argmin + margin flag ----------
// D[code][row] = sum_d E[code][d] * x[row][d] via mfma_f32_16x16x32_f16.
// A = E chunk in LDS (layout [code][d], stride 264 f16, bank-even).
// B = x rows in REGISTERS (wave owns 64 rows, full K=256 -> 128 VGPRs).
// score s = cn[code] - 2*sim (row-constant ||x||^2 dropped; rescue re-adds).
__global__ __launch_bounds__(256) void vq_argmin(const float* __restrict__ x,
                                                 const _Float16* __restrict__ ef,
                                                 const float* __restrict__ cn,
                                                 int* __restrict__ idx_out,
                                                 int* __restrict__ counter,
                                                 int* __restrict__ list) {
    __shared__ _Float16 Elds[64 * 264];   // 33 KB, +16B row pad
    __shared__ float cnlds[KCODE];        // 4 KB

    const int tid  = threadIdx.x;
    const int lane = tid & 63;
    const int wave = tid >> 6;
    const int lo   = lane & 15;      // row-in-tile / code-in-tile low bits
    const int q    = lane >> 4;      // k-quad (0..3)
    const int n0   = blockIdx.x * 256 + wave * 64;   // wave's first row

    // stage cn once
#pragma unroll
    for (int i = 0; i < 4; ++i) cnlds[tid + i * 256] = cn[tid + i * 256];

    // ---- load x rows into B-fragments (f16, registers) ----
    // B[k=d][n=row]: n = lane&15 within ntile, k = q*8 + j within kstep*32
    half8 xb[4][8];   // [ntile][kstep] = 128 VGPRs
#pragma unroll
    for (int nt = 0; nt < 4; ++nt) {
        const float* rowp = x + (size_t)(n0 + nt * 16 + lo) * DIM + q * 8;
#pragma unroll
        for (int ks = 0; ks < 8; ++ks) {
            float4 a = *(const float4*)(rowp + ks * 32);
            float4 b = *(const float4*)(rowp + ks * 32 + 4);
            half8 h;
            h[0] = (_Float16)a.x; h[1] = (_Float16)a.y;
            h[2] = (_Float16)a.z; h[3] = (_Float16)a.w;
            h[4] = (_Float16)b.x; h[5] = (_Float16)b.y;
            h[6] = (_Float16)b.z; h[7] = (_Float16)b.w;
            xb[nt][ks] = h;
        }
    }

    float best[4], sec[4];
    int   bidx[4];
#pragma unroll
    for (int nt = 0; nt < 4; ++nt) {
        best[nt] = 3.402823466e38f; sec[nt] = 3.402823466e38f; bidx[nt] = 0;
    }

    // prefetch E chunk 0: 64 codes x 256 d f16 = 32 KB; 8x16B per thread
    float4 pf[8];
#pragma unroll
    for (int i = 0; i < 8; ++i) {
        int c = i * 256 + tid;                    // chunk id (code = c>>5, col = c&31)
        pf[i] = *(const float4*)&ef[(size_t)(c >> 5) * DIM + (c & 31) * 8];
    }

    for (int s = 0; s < 16; ++s) {                // 16 super-chunks of 64 codes
        __syncthreads();                          // prior chunk reads done
#pragma unroll
        for (int i = 0; i < 8; ++i) {
            int c = i * 256 + tid;
            *(float4*)&Elds[(c >> 5) * 264 + (c & 31) * 8] = pf[i];
        }
        if (s < 15) {
#pragma unroll
            for (int i = 0; i < 8; ++i) {
                int c = i * 256 + tid;
                pf[i] = *(const float4*)&ef[(size_t)((s + 1) * 64 + (c >> 5)) * DIM + (c & 31) * 8];
            }
        }
        __syncthreads();

#pragma unroll
        for (int ktl = 0; ktl < 2; ++ktl) {       // 2 code-tiles of 32 per chunk
            f32x4 acc[2][4];
#pragma unroll
            for (int m = 0; m < 2; ++m)
#pragma unroll
                for (int nt = 0; nt < 4; ++nt)
                    acc[m][nt] = (f32x4){0.f, 0.f, 0.f, 0.f};

#pragma unroll
            for (int ks = 0; ks < 8; ++ks) {
                half8 ea0 = *(half8*)&Elds[(ktl * 32 + lo) * 264 + ks * 32 + q * 8];
                half8 ea1 = *(half8*)&Elds[(ktl * 32 + 16 + lo) * 264 + ks * 32 + q * 8];
#pragma unroll
                for (int nt = 0; nt < 4; ++nt) {
                    acc[0][nt] = __builtin_amdgcn_mfma_f32_16x16x32_f16(ea0, xb[nt][ks], acc[0][nt], 0, 0, 0);
                    acc[1][nt] = __builtin_amdgcn_mfma_f32_16x16x32_f16(ea1, xb[nt][ks], acc[1][nt], 0, 0, 0);
                }
            }
            // epilogue: fold 32 codes into running best/sec per row
            int cb = s * 64 + ktl * 32;
#pragma unroll
            for (int m = 0; m < 2; ++m) {
                int cbase = cb + m * 16 + q * 4;   // C/D: code = (lane>>4)*4 + reg
                f32x4 cnv = *(f32x4*)&cnlds[cbase];
#pragma unroll
                for (int nt = 0; nt < 4; ++nt) {
#pragma unroll
                    for (int r = 0; r < 4; ++r) {
                        float sd = __builtin_fmaf(-2.f, acc[m][nt][r], cnv[r]);
                        bool lt = sd < best[nt];
                        sec[nt]  = fminf(sec[nt], fmaxf(best[nt], sd));
                        bidx[nt] = lt ? (cbase + r) : bidx[nt];
                        best[nt] = fminf(best[nt], sd);
                    }
                }
            }
        }
    }

    // cross-lane merge: row candidates live in lanes {lo, lo+16, lo+32, lo+48}
#pragma unroll
    for (int nt = 0; nt < 4; ++nt) {
        float b = best[nt], sc = sec[nt];
        int   id = bidx[nt];
#pragma unroll
        for (int off = 16; off <= 32; off <<= 1) {
            float b2 = __shfl_xor(b, off);
            float s2 = __shfl_xor(sc, off);
            int   i2 = __shfl_xor(id, off);
            sc = fminf(fminf(sc, s2), fmaxf(b, b2));
            id = (b2 < b) ? i2 : id;   // exact tie -> flagged below, rescue fixes
            b  = fminf(b, b2);
        }
        if (lane < 16) {
            int row = n0 + nt * 16 + lane;
            idx_out[row] = id;
            if (sc - b < MARGIN) {
                int p = atomicAdd(counter, 1);
                if (p < NROWS) list[p] = row;
            }
        }
    }
}

// ---------------- np-exact rescue for flagged rows ----------------
// Recomputes all 1024 dists with numpy's exact fp32 pipeline:
// rn via pairwise/AVX512 tree, sim via sequential fmaf, dist = fl(fl(rn+cn)-2s).
__global__ __launch_bounds__(256) void vq_rescue(const float* __restrict__ x,
                                                 const float* __restrict__ emb,
                                                 const float* __restrict__ cn,
                                                 const int* __restrict__ list,
                                                 const int* __restrict__ counter,
                                                 int* __restrict__ idx) {
#pragma clang fp contract(off)
    __shared__ float xs[DIM];
    __shared__ float rnS;
    __shared__ float bv[256];
    __shared__ int   bk[256];
    int cnt = counter[0];
    if (cnt > NROWS) cnt = NROWS;
    for (int li = blockIdx.x; li < cnt; li += gridDim.x) {
        int row = list[li];
        __syncthreads();
        xs[threadIdx.x] = x[(size_t)row * DIM + threadIdx.x];
        __syncthreads();
        // rn: numpy pairwise(256)=128+128, AVX512 16-lane tree (threads 0..15)
        if (threadIdx.x < 16) {
            int l = threadIdx.x;
            float blk[2];
#pragma unroll
            for (int b = 0; b < 2; ++b) {
                const float* p = xs + b * 128 + l;
                float a0 = p[0],  a4 = p[64];
                float a1 = p[16], a5 = p[80];
                float a2 = p[32], a6 = p[96];
                float a3 = p[48], a7 = p[112];
                float s0 = a0 * a0, s4 = a4 * a4;
                float s1 = a1 * a1, s5 = a5 * a5;
                float s2 = a2 * a2, s6 = a6 * a6;
                float s3 = a3 * a3, s7 = a7 * a7;
                float r0 = s0 + s4;
                float r1 = s1 + s5;
                float r2 = s2 + s6;
                float r3 = s3 + s7;
                float v = (r0 + r1) + (r2 + r3);
                float u = v + __shfl_down(v, 8, 16);
                float w = u + __shfl_down(u, 4, 16);
                float t = w + __shfl_down(w, 2, 16);
                float z = t + __shfl_down(t, 1, 16);
                blk[b] = z;
            }
            if (l == 0) rnS = blk[0] + blk[1];
        }
        __syncthreads();
        float rnv = rnS;
        float bvl = 3.402823466e38f;
        int   bkl = 0;
#pragma unroll
        for (int kk = 0; kk < 4; ++kk) {
            int k = kk * 256 + threadIdx.x;       // ascending per thread
            float sim = 0.f;
            for (int d = 0; d < DIM; ++d)
                sim = __builtin_fmaf(xs[d], emb[d * KCODE + k], sim);
            float t = rnv + cn[k];                // fl(rn + cn)
            float dist = t - 2.f * sim;           // 2*sim exact -> one rounding
            if (dist < bvl) { bvl = dist; bkl = k; }
        }
        bv[threadIdx.x] = bvl; bk[threadIdx.x] = bkl;
        __syncthreads();
        if (threadIdx.x == 0) {
            float b = bv[0]; int kbest = bk[0];
            for (int t = 1; t < 256; ++t)
                if (bv[t] < b || (bv[t] == b && bk[t] < kbest)) { b = bv[t]; kbest = bk[t]; }
            idx[row] = kbest;
        }
        __syncthreads();
    }
}

// ---------------- gather + loss (grid-stride, 1 atomic/block) ----------------
__global__ __launch_bounds__(256) void vq_gather(const float* __restrict__ x,
                                                 const float* __restrict__ et,
                                                 const int* __restrict__ idx,
                                                 float* __restrict__ out,
                                                 float* __restrict__ loss_acc) {
    const int tid = threadIdx.x;
    float lsum = 0.f;
#pragma unroll
    for (int it = 0; it < 8; ++it) {
        size_t g   = (size_t)blockIdx.x * 256 + tid + (size_t)it * (2048 * 256);
        int    row = (int)(g >> 6);          // 64 float4 per row
        int    d4  = (int)(g & 63);
        int    k   = idx[row];               // wave-uniform broadcast
        float4 q4  = *(const float4*)&et[(size_t)k * DIM + d4 * 4];
        float4 x4  = *(const float4*)&x[g * 4];
        float d0 = q4.x - x4.x, d1 = q4.y - x4.y;
        float d2 = q4.z - x4.z, d3 = q4.w - x4.w;
        float4 o4 = make_float4(x4.x + d0, x4.y + d1, x4.z + d2, x4.w + d3);
        *(float4*)&out[g * 4] = o4;
        lsum += d0 * d0 + d1 * d1 + d2 * d2 + d3 * d3;
    }
#pragma unroll
    for (int off = 32; off > 0; off >>= 1) lsum += __shfl_down(lsum, off);
    __shared__ float w4[4];
    if ((tid & 63) == 0) w4[tid >> 6] = lsum;
    __syncthreads();
    if (tid == 0) atomicAdd(loss_acc, w4[0] + w4[1] + w4[2] + w4[3]);
}

__global__ void vq_finalize(const float* __restrict__ loss_acc,
                            float* __restrict__ out) {
    // loss = (BETA + 1) * mean((q-x)^2) = 1.25 * sum / NUMEL
    out[NUMEL] = 1.25f * loss_acc[0] / 16777216.f;
}

// ---------------- launch ----------------
extern "C" void kernel_launch(void* const* d_in, const int* in_sizes, int n_in,
                              void* d_out, int out_size, void* d_ws, size_t ws_size,
                              hipStream_t stream) {
    const float* x   = (const float*)d_in[0];   // [65536][256]
    const float* emb = (const float*)d_in[1];   // [256][1024]
    float* out = (float*)d_out;                 // [NUMEL] quantized + [1] loss

    // ws: et 1MB | ef16 512KB | cn 4KB | idx 256KB | loss 4 | counter 4 | list 256KB
    char* ws = (char*)d_ws;
    size_t off = 0;
    float*     et       = (float*)(ws + off);     off += (size_t)KCODE * DIM * 4;
    _Float16*  ef       = (_Float16*)(ws + off);  off += (size_t)KCODE * DIM * 2;
    float*     cn       = (float*)(ws + off);     off += KCODE * 4;
    int*       idx      = (int*)(ws + off);       off += (size_t)NROWS * 4;
    float*     loss_acc = (float*)(ws + off);     off += 4;
    int*       counter  = (int*)(ws + off);       off += 4;
    int*       list     = (int*)(ws + off);

    hipMemsetAsync(loss_acc, 0, 8, stream);      // zero loss + counter
    vq_prep_te<<<256,  256, 0, stream>>>(emb, et, ef);
    vq_prep_cn<<<4,    256, 0, stream>>>(emb, cn);
    vq_argmin <<<256,  256, 0, stream>>>(x, ef, cn, idx, counter, list);
    vq_rescue <<<1024, 256, 0, stream>>>(x, emb, cn, list, counter, idx);
    vq_gather <<<2048, 256, 0, stream>>>(x, et, idx, out, loss_acc);
    vq_finalize<<<1, 1, 0, stream>>>(loss_acc, out);
}